// Round 5
// baseline (399.590 us; speedup 1.0000x reference)
//
#include <hip/hip_runtime.h>
#include <hip/hip_bf16.h>

typedef __bf16 bf16x8 __attribute__((ext_vector_type(8)));
typedef float f32x4 __attribute__((ext_vector_type(4)));

static constexpr int Tn = 8192;
static constexpr int Cn = 1024;

#define DEVI __device__ __forceinline__

DEVI float bf2f(ushort u) { union { uint i; float f; } c; c.i = ((uint)u) << 16; return c.f; }
DEVI ushort f2bf(float f) {
  uint x = __builtin_bit_cast(uint, f);
  x += 0x7fffu + ((x >> 16) & 1u);   // RNE
  return (ushort)(x >> 16);
}

typedef const __attribute__((address_space(1))) void glb_v;
typedef __attribute__((address_space(3))) void lds_v;

// ---------------------------------------------------------------- cast + concat
__global__ __launch_bounds__(256) void cast_all(
    const float* __restrict__ x, const float* __restrict__ wq, const float* __restrict__ wk,
    const float* __restrict__ wv, const float* __restrict__ wp,
    const float* __restrict__ bq, const float* __restrict__ bk, const float* __restrict__ bv,
    ushort* __restrict__ xb, ushort* __restrict__ wqkv, ushort* __restrict__ wpb,
    float* __restrict__ bqkv)
{
  const long long NX = (long long)Tn * Cn;
  const long long NW = (long long)Cn * Cn;      // 2^20
  if (blockIdx.x >= 12288) {   // bias concat
    int id = ((blockIdx.x - 12288) * 256 + threadIdx.x) * 4;
#pragma unroll
    for (int e = 0; e < 4; ++e) {
      int j = id + e;
      if (j < 3 * Cn) bqkv[j] = j < Cn ? bq[j] : (j < 2 * Cn ? bk[j - Cn] : bv[j - 2 * Cn]);
    }
    return;
  }
  long long i = ((long long)blockIdx.x * 256 + threadIdx.x) * 4;
  const float* src; ushort* dst; long long off;
  if (i < NX) { src = x; dst = xb; off = i; }
  else {
    long long r = i - NX; int seg = (int)(r >> 20); off = r & (NW - 1);
    if (seg < 3) { src = seg == 0 ? wq : seg == 1 ? wk : wv; dst = wqkv + (size_t)seg * NW; }
    else         { src = wp; dst = wpb; }
  }
  float4 v = *reinterpret_cast<const float4*>(src + off);
  ushort4 o; o.x = f2bf(v.x); o.y = f2bf(v.y); o.z = f2bf(v.z); o.w = f2bf(v.w);
  *reinterpret_cast<ushort4*>(dst + off) = o;
}

// ---------------------------------------------------------------- TLP GEMM engine
// C[M,N] = A[M,K] @ Bt[N,K]^T.  128x128 tile, BK=64, 4 waves (2x2), single
// 32KB LDS buffer (4-5 blocks/CU co-resident: cross-block overlap hides the
// per-K-step vmcnt drain — the m97/m114 mechanism).  Chunk-XOR LDS swizzle
// (0 bank conflicts, verified R1-R4).
// TRI: 1-D triangular grid (only causal blocks), XCD-swizzled.
// PVMODE: by reversed (longest K first) + causal K-limit.
// SPLIT3: N=3072 QKV output split into 3 separate [Tn,Cn] buffers.
template<bool OUT_BF16, bool HAS_BIAS, bool TRI, bool PVMODE, bool SPLIT3>
__global__ __launch_bounds__(256)
void gemm_tlp(const ushort* __restrict__ A, const ushort* __restrict__ Bt,
              const float* __restrict__ bias, void* __restrict__ outp,
              int K, int lda, int ldb, int ldc, float scale)
{
  __shared__ __align__(16) ushort Als[128 * 64];
  __shared__ __align__(16) ushort Bls[128 * 64];

  const int tid = threadIdx.x;
  const int lane = tid & 63, wid = tid >> 6;
  const int wr = (wid >> 1) * 64, wc = (wid & 1) * 64;
  const int ln15 = lane & 15, lhi = lane >> 4;

  int bx, by;
  if (TRI) {
    // XCD swizzle (bijective: gridDim.x % 8 == 0), then triangular decode
    int id = blockIdx.x;
    int sw = (id & 7) * ((int)gridDim.x >> 3) + (id >> 3);
    float ff = __builtin_sqrtf(8.f * (float)sw + 1.f);
    by = (int)((ff - 1.f) * 0.5f);
    while ((by + 1) * (by + 2) / 2 <= sw) ++by;
    while (by * (by + 1) / 2 > sw) --by;
    bx = sw - by * (by + 1) / 2;
  } else {
    bx = blockIdx.x;
    by = PVMODE ? ((int)gridDim.y - 1 - (int)blockIdx.y) : (int)blockIdx.y;
  }

  const int rowA0 = by * 128, col0 = bx * 128;
  int NT = K >> 6;
  if (PVMODE) { int kl = (by + 1) * 128; if (kl < K) NT = kl >> 6; }

  f32x4 acc[4][4] = {};

  for (int kt = 0; kt < NT; ++kt) {
    const int k0 = kt << 6;
#pragma unroll
    for (int i = 0; i < 4; ++i) {
      int c = tid + i * 256;
      int row = c >> 3, kc = c & 7;
      int kcs = kc ^ (row & 7);
      const ushort* ga = A + (size_t)(rowA0 + row) * (size_t)lda + (k0 + kcs * 8);
      const ushort* gb = Bt + (size_t)(col0 + row) * (size_t)ldb + (k0 + kcs * 8);
      __builtin_amdgcn_global_load_lds((glb_v*)ga, (lds_v*)(&Als[c * 8]), 16, 0, 0);
      __builtin_amdgcn_global_load_lds((glb_v*)gb, (lds_v*)(&Bls[c * 8]), 16, 0, 0);
    }
    __syncthreads();
#pragma unroll
    for (int kk = 0; kk < 2; ++kk) {
      bf16x8 af[4], bfr[4];
#pragma unroll
      for (int mi = 0; mi < 4; ++mi) {
        int r = wr + mi * 16 + ln15;
        int kc = kk * 4 + lhi;
        af[mi] = *reinterpret_cast<const bf16x8*>(&Als[(r * 8 + (kc ^ (r & 7))) * 8]);
      }
#pragma unroll
      for (int ni = 0; ni < 4; ++ni) {
        int r = wc + ni * 16 + ln15;
        int kc = kk * 4 + lhi;
        bfr[ni] = *reinterpret_cast<const bf16x8*>(&Bls[(r * 8 + (kc ^ (r & 7))) * 8]);
      }
#pragma unroll
      for (int mi = 0; mi < 4; ++mi)
#pragma unroll
        for (int ni = 0; ni < 4; ++ni)
          acc[mi][ni] = __builtin_amdgcn_mfma_f32_16x16x32_bf16(af[mi], bfr[ni], acc[mi][ni], 0, 0, 0);
    }
    __syncthreads();
  }

  // epilogue: C col = lane&15, row = (lane>>4)*4 + reg
#pragma unroll
  for (int ni = 0; ni < 4; ++ni) {
    int colg = col0 + wc + ni * 16 + ln15;          // global col (0..N-1)
    float bv = HAS_BIAS ? bias[colg] : 0.f;
    int col = colg;
    size_t segoff = 0;
    if (SPLIT3) { int seg = colg >> 10; col = colg & 1023; segoff = (size_t)seg * (size_t)Tn * Cn; }
#pragma unroll
    for (int mi = 0; mi < 4; ++mi) {
      f32x4 v = acc[mi][ni];
      int r0 = rowA0 + wr + mi * 16 + lhi * 4;
#pragma unroll
      for (int j = 0; j < 4; ++j) {
        float val = v[j] * scale + bv;
        if (OUT_BF16) ((ushort*)outp)[segoff + (size_t)(r0 + j) * (size_t)ldc + col] = f2bf(val);
        else          ((float*)outp)[segoff + (size_t)(r0 + j) * (size_t)ldc + col] = val;
      }
    }
  }
}

// ---------------------------------------------------------------- transpose (bf16), 64x64 tiles
__global__ __launch_bounds__(256) void transpose64(const ushort* __restrict__ in,
                                                   ushort* __restrict__ out,
                                                   int ldin, int ldout)
{
  __shared__ ushort tile[64][65];
  const int c0 = blockIdx.x * 64, r0 = blockIdx.y * 64;
  const int t = threadIdx.x;
#pragma unroll
  for (int i = t; i < 512; i += 256) {
    int r = i >> 3, kc = i & 7;
    uint4 v = *reinterpret_cast<const uint4*>(in + (size_t)(r0 + r) * ldin + c0 + kc * 8);
    const ushort* u = reinterpret_cast<const ushort*>(&v);
#pragma unroll
    for (int j = 0; j < 8; ++j) tile[r][kc * 8 + j] = u[j];
  }
  __syncthreads();
#pragma unroll
  for (int i = t; i < 512; i += 256) {
    int c = i >> 3, rc = i & 7;
    union { uint4 v; ushort u[8]; } pk;
#pragma unroll
    for (int j = 0; j < 8; ++j) pk.u[j] = tile[rc * 8 + j][c];
    *reinterpret_cast<uint4*>(out + (size_t)(c0 + c) * ldout + r0 + rc * 8) = pk.v;
  }
}

// ---------------------------------------------------------------- causal softmax, in place
__global__ __launch_bounds__(256) void softmax_causal(ushort* __restrict__ S, int Td)
{
  const int t = blockIdx.x;
  const int tid = threadIdx.x;
  ushort* row = S + (size_t)t * Td;
  const int L = t + 1;
  const int Lv = L & ~7;

  float sum = 0.f;
  for (int j = tid * 8; j < Lv; j += 2048) {
    uint4 v = *reinterpret_cast<const uint4*>(row + j);
    const ushort* u = reinterpret_cast<const ushort*>(&v);
#pragma unroll
    for (int e = 0; e < 8; ++e) sum += __expf(bf2f(u[e]));
  }
  for (int j = Lv + tid; j < L; j += 256) sum += __expf(bf2f(row[j]));

#pragma unroll
  for (int off = 32; off; off >>= 1) sum += __shfl_down(sum, off);
  __shared__ float red[4];
  if ((tid & 63) == 0) red[tid >> 6] = sum;
  __syncthreads();
  const float inv = 1.f / (red[0] + red[1] + red[2] + red[3]);

  for (int j = tid * 8; j < Lv; j += 2048) {
    uint4 v = *reinterpret_cast<const uint4*>(row + j);
    union { uint4 v; ushort u[8]; } pk;
    const ushort* u = reinterpret_cast<const ushort*>(&v);
#pragma unroll
    for (int e = 0; e < 8; ++e) pk.u[e] = f2bf(__expf(bf2f(u[e])) * inv);
    *reinterpret_cast<uint4*>(row + j) = pk.v;
  }
  for (int j = Lv + tid; j < L; j += 256) row[j] = f2bf(__expf(bf2f(row[j])) * inv);

  const int Za = (L + 7) & ~7;
  for (int j = L + tid; j < Za; j += 256) row[j] = 0;
  uint4 z; z.x = z.y = z.z = z.w = 0u;
  for (int j = Za + tid * 8; j < Td; j += 2048) *reinterpret_cast<uint4*>(row + j) = z;
}

// ---------------------------------------------------------------- launch
extern "C" void kernel_launch(void* const* d_in, const int* in_sizes, int n_in,
                              void* d_out, int out_size, void* d_ws, size_t ws_size,
                              hipStream_t stream)
{
  (void)in_sizes; (void)n_in; (void)out_size; (void)ws_size;
  const float* x  = (const float*)d_in[0];
  const float* Wq = (const float*)d_in[1];
  const float* bq = (const float*)d_in[2];
  const float* Wk = (const float*)d_in[3];
  const float* bk = (const float*)d_in[4];
  const float* Wv = (const float*)d_in[5];
  const float* bv = (const float*)d_in[6];
  const float* Wp = (const float*)d_in[7];
  const float* bp = (const float*)d_in[8];

  char* w = (char*)d_ws;
  const size_t TC = (size_t)Tn * Cn * 2, CC = (size_t)Cn * Cn * 2;
  ushort* xb   = (ushort*)w; w += TC;                    // 16 MB
  ushort* Wqkv = (ushort*)w; w += 3 * CC;                // 6 MB
  ushort* wpb  = (ushort*)w; w += CC;                    // 2 MB
  float*  bqkv = (float*)w;  w += 3 * Cn * 4 + 4096;     // 12 KB
  ushort* Qb   = (ushort*)w; w += TC;                    // 16 MB  (Q,K,V contiguous)
  ushort* Kb   = (ushort*)w; w += TC;                    // 16 MB
  ushort* Vb   = (ushort*)w; w += TC;                    // 16 MB
  ushort* Vt   = (ushort*)w; w += TC;                    // 16 MB
  ushort* Yb   = (ushort*)w; w += TC;                    // 16 MB
  ushort* S    = (ushort*)w; w += (size_t)Tn * Tn * 2;   // 128 MB

  cast_all<<<12291, 256, 0, stream>>>(x, Wq, Wk, Wv, Wp, bq, bk, bv, xb, Wqkv, wpb, bqkv);

  // QKV fused GEMM, output split to separate Q,K,V buffers (unstrided, ldc=1024)
  gemm_tlp<true, true, false, false, true><<<dim3(24, 64), 256, 0, stream>>>(
      xb, Wqkv, bqkv, Qb, Cn, Cn, Cn, Cn, 1.0f);

  // V^T for the PV GEMM
  transpose64<<<dim3(Cn / 64, Tn / 64), 256, 0, stream>>>(Vb, Vt, Cn, Tn);

  // S = Q @ K^T / 32  — triangular 1-D grid (2080 = 8*260 blocks), XCD-swizzled
  gemm_tlp<true, false, true, false, false><<<dim3(2080, 1), 256, 0, stream>>>(
      Qb, Kb, nullptr, S, Cn, Cn, Cn, Tn, 0.03125f);

  softmax_causal<<<Tn, 256, 0, stream>>>(S, Tn);

  // Y = P @ V  (longest-K rows first, causal K-limit)
  gemm_tlp<true, false, false, true, false><<<dim3(8, 64), 256, 0, stream>>>(
      S, Vt, nullptr, Yb, Tn, Tn, Tn, Cn, 1.0f);

  // out = Y @ Wp^T + bp (fp32 out)
  gemm_tlp<false, true, false, false, false><<<dim3(8, 64), 256, 0, stream>>>(
      Yb, wpb, bp, d_out, Cn, Cn, Cn, Cn, 1.0f);
}

// Round 6
// 322.673 us; speedup vs baseline: 1.2384x; 1.2384x over previous
//
#include <hip/hip_runtime.h>
#include <hip/hip_bf16.h>

typedef __bf16 bf16x8 __attribute__((ext_vector_type(8)));
typedef float f32x4 __attribute__((ext_vector_type(4)));

static constexpr int Tn = 8192;
static constexpr int Cn = 1024;

#define DEVI __device__ __forceinline__

DEVI float bf2f(ushort u) { union { uint i; float f; } c; c.i = ((uint)u) << 16; return c.f; }
DEVI ushort f2bf(float f) {
  uint x = __builtin_bit_cast(uint, f);
  x += 0x7fffu + ((x >> 16) & 1u);   // RNE
  return (ushort)(x >> 16);
}

typedef const __attribute__((address_space(1))) void glb_v;
typedef __attribute__((address_space(3))) void lds_v;

#define BAR()   __builtin_amdgcn_s_barrier()
#define SCH0()  __builtin_amdgcn_sched_barrier(0)
#define PRIO1() __builtin_amdgcn_s_setprio(1)
#define PRIO0() __builtin_amdgcn_s_setprio(0)

// ---------------------------------------------------------------- cast + concat + l-zero
__global__ __launch_bounds__(256) void cast_all(
    const float* __restrict__ x, const float* __restrict__ wq, const float* __restrict__ wk,
    const float* __restrict__ wv, const float* __restrict__ wp,
    const float* __restrict__ bq, const float* __restrict__ bk, const float* __restrict__ bv,
    ushort* __restrict__ xb, ushort* __restrict__ wqkv, ushort* __restrict__ wpb,
    float* __restrict__ bqkv, float* __restrict__ lsum)
{
  const long long NX = (long long)Tn * Cn;
  const long long NW = (long long)Cn * Cn;      // 2^20
  if (blockIdx.x == 12291) {   // zero the softmax-denominator accumulator
    float4 z; z.x = z.y = z.z = z.w = 0.f;
#pragma unroll
    for (int j = 0; j < 8; ++j) ((float4*)lsum)[threadIdx.x * 8 + j] = z;
    return;
  }
  if (blockIdx.x >= 12288) {   // bias concat (3 blocks)
    int id = ((blockIdx.x - 12288) * 256 + threadIdx.x) * 4;
#pragma unroll
    for (int e = 0; e < 4; ++e) {
      int j = id + e;
      if (j < 3 * Cn) bqkv[j] = j < Cn ? bq[j] : (j < 2 * Cn ? bk[j - Cn] : bv[j - 2 * Cn]);
    }
    return;
  }
  long long i = ((long long)blockIdx.x * 256 + threadIdx.x) * 4;
  const float* src; ushort* dst; long long off;
  if (i < NX) { src = x; dst = xb; off = i; }
  else {
    long long r = i - NX; int seg = (int)(r >> 20); off = r & (NW - 1);
    if (seg < 3) { src = seg == 0 ? wq : seg == 1 ? wk : wv; dst = wqkv + (size_t)seg * NW; }
    else         { src = wp; dst = wpb; }
  }
  float4 v = *reinterpret_cast<const float4*>(src + off);
  ushort4 o; o.x = f2bf(v.x); o.y = f2bf(v.y); o.z = f2bf(v.z); o.w = f2bf(v.w);
  *reinterpret_cast<ushort4*>(dst + off) = o;
}

// ---------------------------------------------------------------- register-pipelined GEMM
// C[M,N] = A[M,K] @ Bt[N,K]^T. 128x128 tile, 4 waves (2x2, per-wave 64x64),
// BK=64, double-buffered 64KB LDS (2 blocks/CU). asm ds_read_b128 pipeline:
//  per K-tile t (buf b): issue slice1(t) reads -> lgkmcnt(8) [slice0 landed] ->
//  MFMA slice0 -> lgkmcnt(0) -> BAR [buf b free] -> stage(t+2 -> buf b) ->
//  vmcnt(8) [t+1 landed, t+2 in flight] -> BAR -> issue slice0(t+1) reads ->
//  MFMA slice1.  vmcnt never drains to 0 in-loop; every MFMA cluster sits
//  behind an explicit counted wait + sched_barrier (rule #18).
// QKT: causal skip, epilogue exp(s*scale) + mask + atomic row-sum into lsum.
// PVM: by reversed, causal K-limit, epilogue * (1/lsum[row]).
template<bool OUT_BF16, bool HAS_BIAS, bool QKT, bool PVM, bool SPLIT3>
__global__ __launch_bounds__(256, 2)
void gemm_rp(const ushort* __restrict__ A, const ushort* __restrict__ Bt,
             const float* __restrict__ bias, void* __restrict__ outp,
             float* __restrict__ lsum,
             int K, int lda, int ldb, int ldc, float scale)
{
  __shared__ __align__(16) ushort sm[32768];   // 2 bufs x (A 8192 + B 8192) = 64 KB

  const int tid = threadIdx.x, lane = tid & 63, wid = tid >> 6;
  const int wm = wid >> 1, wn = wid & 1;
  const int ln15 = lane & 15, lsec = lane >> 4;

  const int bx = blockIdx.x;
  int by = blockIdx.y;
  if (QKT && by < bx) return;
  if (PVM) by = (int)gridDim.y - 1 - by;
  const int rowA0 = by * 128, col0 = bx * 128;
  int NT = K >> 6;
  if (PVM) { int kl = (by + 1) * 128; if (kl < K) NT = kl >> 6; }

  const uint smb = (uint)(uintptr_t)&sm[0];

  // staging: 8 x global_load_lds(16B) per tile; dst = uniform base + lane*16
  auto stage = [&](int t, int b) {
    const int tt = t < NT ? t : NT - 1;
    const size_t k0 = (size_t)(tt << 6);
#pragma unroll
    for (int i = 0; i < 4; ++i) {
      int s = tid + i * 256; int row = s >> 3; int kcs = (s & 7) ^ (row & 7);
      const ushort* g = A + (size_t)(rowA0 + row) * (size_t)lda + k0 + kcs * 8;
      __builtin_amdgcn_global_load_lds((glb_v*)g, (lds_v*)(&sm[b * 16384 + s * 8]), 16, 0, 0);
    }
#pragma unroll
    for (int i = 0; i < 4; ++i) {
      int s = tid + i * 256; int row = s >> 3; int kcs = (s & 7) ^ (row & 7);
      const ushort* g = Bt + (size_t)(col0 + row) * (size_t)ldb + k0 + kcs * 8;
      __builtin_amdgcn_global_load_lds((glb_v*)g, (lds_v*)(&sm[b * 16384 + 8192 + s * 8]), 16, 0, 0);
    }
  };

  // precomputed LDS byte offsets (within a buffer) for each fragment
  uint offA[2][4], offB[2][4];
#pragma unroll
  for (int ks = 0; ks < 2; ++ks) {
    int kc = ks * 4 + lsec;
#pragma unroll
    for (int mi = 0; mi < 4; ++mi) {
      int r = wm * 64 + mi * 16 + ln15;
      offA[ks][mi] = (uint)((r * 64 + (kc ^ (r & 7)) * 8) * 2);
    }
#pragma unroll
    for (int ni = 0; ni < 4; ++ni) {
      int c = wn * 64 + ni * 16 + ln15;
      offB[ks][ni] = (uint)(16384 + (c * 64 + (kc ^ (c & 7)) * 8) * 2);
    }
  }

  bf16x8 f0A[4], f0B[4], f1A[4], f1B[4];
  f32x4 acc[4][4] = {};

#define DSR(d, a) asm volatile("ds_read_b128 %0, %1" : "=v"(d) : "v"(a))
#define MMAC(FA, FB) { _Pragma("unroll") for (int mi = 0; mi < 4; ++mi) \
    _Pragma("unroll") for (int ni = 0; ni < 4; ++ni) \
      acc[mi][ni] = __builtin_amdgcn_mfma_f32_16x16x32_bf16(FA[mi], FB[ni], acc[mi][ni], 0, 0, 0); }

  // prologue: tiles 0,1 in flight; tile0 landed; slice0(0) reads issued
  stage(0, 0); stage(1, 1);
  asm volatile("s_waitcnt vmcnt(8)" ::: "memory");   // tile0's 8 landed
  BAR();
  SCH0();
#pragma unroll
  for (int mi = 0; mi < 4; ++mi) DSR(f0A[mi], smb + offA[0][mi]);
#pragma unroll
  for (int ni = 0; ni < 4; ++ni) DSR(f0B[ni], smb + offB[0][ni]);
  SCH0();

  uint boff = 0;
  for (int t = 0; t < NT; ++t, boff ^= 32768u) {
    // slice1(t) reads — in flight during MFMA slice0
#pragma unroll
    for (int mi = 0; mi < 4; ++mi) DSR(f1A[mi], smb + boff + offA[1][mi]);
#pragma unroll
    for (int ni = 0; ni < 4; ++ni) DSR(f1B[ni], smb + boff + offB[1][ni]);
    SCH0();
    asm volatile("s_waitcnt lgkmcnt(8)" ::: "memory");   // slice0 regs ready
    SCH0();
    PRIO1(); MMAC(f0A, f0B); PRIO0();
    SCH0();
    asm volatile("s_waitcnt lgkmcnt(0)" ::: "memory");   // slice1 regs ready
    BAR();                                               // all done reading buf b
    stage(t + 2, t & 1);                                 // overwrite buf b
    SCH0();
    asm volatile("s_waitcnt vmcnt(8)" ::: "memory");     // tile t+1 fully landed
    BAR();
    SCH0();
    const uint bo1 = boff ^ 32768u;
#pragma unroll
    for (int mi = 0; mi < 4; ++mi) DSR(f0A[mi], smb + bo1 + offA[0][mi]);
#pragma unroll
    for (int ni = 0; ni < 4; ++ni) DSR(f0B[ni], smb + bo1 + offB[0][ni]);
    SCH0();
    PRIO1(); MMAC(f1A, f1B); PRIO0();
    SCH0();
  }
  asm volatile("s_waitcnt vmcnt(0) lgkmcnt(0)" ::: "memory");
#undef DSR
#undef MMAC

  // ---------------- epilogue: C col = lane&15 (+ni*16), row = lsec*4+j (+mi*16)
  if constexpr (QKT) {
#pragma unroll
    for (int mi = 0; mi < 4; ++mi) {
#pragma unroll
      for (int j = 0; j < 4; ++j) {
        const int row = rowA0 + wm * 64 + mi * 16 + lsec * 4 + j;
        float rs = 0.f;
        ushort pb[4];
#pragma unroll
        for (int ni = 0; ni < 4; ++ni) {
          const int col = col0 + wn * 64 + ni * 16 + ln15;
          float p = 0.f;
          if (col <= row) p = __expf(acc[mi][ni][j] * scale);
          pb[ni] = f2bf(p);
          rs += bf2f(pb[ni]);
        }
#pragma unroll
        for (int o = 1; o < 16; o <<= 1) rs += __shfl_xor(rs, o);
        if (ln15 == 0) atomicAdd(&lsum[row], rs);
#pragma unroll
        for (int ni = 0; ni < 4; ++ni) {
          const int col = col0 + wn * 64 + ni * 16 + ln15;
          ((ushort*)outp)[(size_t)row * (size_t)ldc + col] = pb[ni];
        }
      }
    }
  } else {
#pragma unroll
    for (int mi = 0; mi < 4; ++mi) {
#pragma unroll
      for (int j = 0; j < 4; ++j) {
        const int row = rowA0 + wm * 64 + mi * 16 + lsec * 4 + j;
        float inv = 1.f;
        if constexpr (PVM) inv = 1.0f / lsum[row];
#pragma unroll
        for (int ni = 0; ni < 4; ++ni) {
          const int colg = col0 + wn * 64 + ni * 16 + ln15;
          float val = acc[mi][ni][j] * scale;
          if constexpr (PVM) val *= inv;
          if constexpr (HAS_BIAS) val += bias[colg];
          int col = colg; size_t segoff = 0;
          if constexpr (SPLIT3) { int seg = colg >> 10; col = colg & 1023; segoff = (size_t)seg * (size_t)Tn * Cn; }
          if constexpr (OUT_BF16) ((ushort*)outp)[segoff + (size_t)row * (size_t)ldc + col] = f2bf(val);
          else                    ((float*)outp)[segoff + (size_t)row * (size_t)ldc + col] = val;
        }
      }
    }
  }
}

// ---------------------------------------------------------------- transpose (bf16), 64x64 tiles
__global__ __launch_bounds__(256) void transpose64(const ushort* __restrict__ in,
                                                   ushort* __restrict__ out,
                                                   int ldin, int ldout)
{
  __shared__ ushort tile[64][65];
  const int c0 = blockIdx.x * 64, r0 = blockIdx.y * 64;
  const int t = threadIdx.x;
#pragma unroll
  for (int i = t; i < 512; i += 256) {
    int r = i >> 3, kc = i & 7;
    uint4 v = *reinterpret_cast<const uint4*>(in + (size_t)(r0 + r) * ldin + c0 + kc * 8);
    const ushort* u = reinterpret_cast<const ushort*>(&v);
#pragma unroll
    for (int j = 0; j < 8; ++j) tile[r][kc * 8 + j] = u[j];
  }
  __syncthreads();
#pragma unroll
  for (int i = t; i < 512; i += 256) {
    int c = i >> 3, rc = i & 7;
    union { uint4 v; ushort u[8]; } pk;
#pragma unroll
    for (int j = 0; j < 8; ++j) pk.u[j] = tile[rc * 8 + j][c];
    *reinterpret_cast<uint4*>(out + (size_t)(c0 + c) * ldout + r0 + rc * 8) = pk.v;
  }
}

// ---------------------------------------------------------------- launch
extern "C" void kernel_launch(void* const* d_in, const int* in_sizes, int n_in,
                              void* d_out, int out_size, void* d_ws, size_t ws_size,
                              hipStream_t stream)
{
  (void)in_sizes; (void)n_in; (void)out_size; (void)ws_size;
  const float* x  = (const float*)d_in[0];
  const float* Wq = (const float*)d_in[1];
  const float* bq = (const float*)d_in[2];
  const float* Wk = (const float*)d_in[3];
  const float* bk = (const float*)d_in[4];
  const float* Wv = (const float*)d_in[5];
  const float* bv = (const float*)d_in[6];
  const float* Wp = (const float*)d_in[7];
  const float* bp = (const float*)d_in[8];

  char* w = (char*)d_ws;
  const size_t TC = (size_t)Tn * Cn * 2, CC = (size_t)Cn * Cn * 2;
  ushort* xb   = (ushort*)w; w += TC;                    // 16 MB
  ushort* Wqkv = (ushort*)w; w += 3 * CC;                // 6 MB
  ushort* wpb  = (ushort*)w; w += CC;                    // 2 MB
  float*  bqkv = (float*)w;  w += 16384;                 // 12 KB + pad
  float*  lsum = (float*)w;  w += 32768;                 // 32 KB
  ushort* Qb   = (ushort*)w; w += TC;                    // 16 MB (Q,K,V contiguous)
  ushort* Kb   = (ushort*)w; w += TC;                    // 16 MB
  ushort* Vb   = (ushort*)w; w += TC;                    // 16 MB
  ushort* Vt   = (ushort*)w; w += TC;                    // 16 MB
  ushort* Yb   = (ushort*)w; w += TC;                    // 16 MB
  ushort* S    = (ushort*)w; w += (size_t)Tn * Tn * 2;   // 128 MB

  cast_all<<<12292, 256, 0, stream>>>(x, Wq, Wk, Wv, Wp, bq, bk, bv,
                                      xb, Wqkv, wpb, bqkv, lsum);

  // QKV fused: split-3 epilogue -> Qb,Kb,Vb (grid 1536 = 3 rounds of 2/CU)
  gemm_rp<true, true, false, false, true><<<dim3(24, 64), 256, 0, stream>>>(
      xb, Wqkv, bqkv, Qb, nullptr, Cn, Cn, Cn, Cn, 1.0f);

  // V^T for the PV GEMM
  transpose64<<<dim3(Cn / 64, Tn / 64), 256, 0, stream>>>(Vb, Vt, Cn, Tn);

  // P' = exp(Q@K^T/32) (masked) + atomic row-sums l  (2080 active blocks)
  gemm_rp<true, false, true, false, false><<<dim3(64, 64), 256, 0, stream>>>(
      Qb, Kb, nullptr, S, lsum, Cn, Cn, Cn, Tn, 0.03125f);

  // Y = (P' @ V) / l   (longest-K first, causal K-limit, 512 blocks = 1 round)
  gemm_rp<true, false, false, true, false><<<dim3(8, 64), 256, 0, stream>>>(
      S, Vt, nullptr, Yb, lsum, Tn, Tn, Tn, Cn, 1.0f);

  // out = Y @ Wp^T + bp (fp32 out, 512 blocks = 1 round)
  gemm_rp<false, true, false, false, false><<<dim3(8, 64), 256, 0, stream>>>(
      Yb, wpb, bp, d_out, nullptr, Cn, Cn, Cn, Cn, 1.0f);
}